// Round 10
// baseline (205.470 us; speedup 1.0000x reference)
//
#include <hip/hip_runtime.h>

// Problem constants
#define B_  2
#define S_  2048
#define D_  1024
#define H_  16
#define HD_ 64
#define N3_ 3072      // 3*D
#define M_  4096      // B*S

typedef _Float16 f16;
typedef _Float16 f16x2 __attribute__((ext_vector_type(2)));
typedef _Float16 f16x4 __attribute__((ext_vector_type(4)));
typedef _Float16 f16x8 __attribute__((ext_vector_type(8)));
typedef float    f32x4 __attribute__((ext_vector_type(4)));

// ---------------------------------------------------------------------------
// async global->LDS, 16B per lane. LDS dest must be wave-uniform base+lane*16.
__device__ __forceinline__ void async16(const f16* g, f16* l) {
  __builtin_amdgcn_global_load_lds(
      (const __attribute__((address_space(1))) unsigned int*)g,
      (__attribute__((address_space(3))) unsigned int*)l, 16, 0, 0);
}

__device__ __forceinline__ f16x2 pkrtz(float a, float b) {
  return __builtin_bit_cast(f16x2, __builtin_amdgcn_cvt_pkrtz(a, b));
}

// ---------------------------------------------------------------------------
// One launch converts x AND all 4 weight matrices to f16.
__global__ __launch_bounds__(256)
void cvt_all(const float* __restrict__ x,
             const float* __restrict__ Wq, const float* __restrict__ Wk,
             const float* __restrict__ Wv, const float* __restrict__ Wo,
             f16* __restrict__ xb, f16* __restrict__ wdst, float qscale) {
  const int i = blockIdx.x * 256 + threadIdx.x;
  const int XN4 = M_ * D_ / 4;          // 1048576
  const int WN4 = D_ * D_ / 4;          // 262144 = 2^18
  const float* src;
  f16* dst;
  float scale = 1.0f;
  int j;
  if (i < XN4) {
    src = x; dst = xb; j = i;
  } else {
    int k = i - XN4;
    int m = k >> 18;                    // which weight matrix
    j = k & (WN4 - 1);
    src = (m == 0) ? Wq : (m == 1) ? Wk : (m == 2) ? Wv : Wo;
    if (m == 0) scale = qscale;
    dst = wdst + (size_t)m * D_ * D_;
  }
  float4 v = ((const float4*)src)[j];
  f16x4 o = { (f16)(v.x * scale), (f16)(v.y * scale),
              (f16)(v.z * scale), (f16)(v.w * scale) };
  ((f16x4*)dst)[j] = o;
}

// ---------------------------------------------------------------------------
// QKV GEMM — round-6 single-buffer structure (measured 49.8 µs; dbuf
// regressed to 57.8 by cutting blocks/CU 3->2). 128x128 tile, BK=64,
// stage via async16 between the two barriers. Q/K col-blocks -> f16 Cq
// (mask on K); V col-blocks (n0>=2048) -> V^T into vtout (fused transpose).
__global__ __launch_bounds__(256)
void gemm_qkv(const f16* __restrict__ A, const f16* __restrict__ Bw,
              f16* __restrict__ Cq, f16* __restrict__ vtout,
              const float* __restrict__ mask) {
  __shared__ f16 As[128 * 64];
  __shared__ f16 Bs[128 * 64];

  const int tid  = threadIdx.x;
  const int lane = tid & 63;
  const int w    = tid >> 6;
  const int lcol = lane & 15;
  const int quad = lane >> 4;
  const int lx   = lcol & 7;
  const int wave_m = w >> 1, wave_n = w & 1;

  const int m0 = blockIdx.y * 128;
  const int n0 = blockIdx.x * 128;

  const int rr  = lane >> 3;
  const int gch = (lane & 7) ^ rr;

  const f16* gA[4];
  const f16* gB[4];
  f16* lA[4];
  f16* lB[4];
#pragma unroll
  for (int i = 0; i < 4; i++) {
    int seg = i * 4 + w;
    int row = seg * 8 + rr;
    gA[i] = A  + (size_t)(m0 + row) * D_ + gch * 8;
    gB[i] = Bw + (size_t)(n0 + row) * D_ + gch * 8;
    lA[i] = As + seg * 512;
    lB[i] = Bs + seg * 512;
  }

  int offA[4], offB[4];
#pragma unroll
  for (int i = 0; i < 4; i++) {
    offA[i] = (wave_m * 64 + i * 16 + lcol) * 64;
    offB[i] = (wave_n * 64 + i * 16 + lcol) * 64;
  }

  const f32x4 zero = {0.f, 0.f, 0.f, 0.f};
  f32x4 acc[4][4];
#pragma unroll
  for (int i = 0; i < 4; i++)
#pragma unroll
    for (int j = 0; j < 4; j++) acc[i][j] = zero;

  for (int k0 = 0; k0 < D_; k0 += 64) {
    __syncthreads();
#pragma unroll
    for (int i = 0; i < 4; i++) async16(gA[i] + k0, lA[i]);
#pragma unroll
    for (int i = 0; i < 4; i++) async16(gB[i] + k0, lB[i]);
    __syncthreads();

#pragma unroll
    for (int ks = 0; ks < 2; ks++) {
      const int co = ((quad + 4 * ks) ^ lx) * 8;
      f16x8 af[4], bf[4];
#pragma unroll
      for (int i = 0; i < 4; i++) af[i] = *(const f16x8*)(As + offA[i] + co);
#pragma unroll
      for (int i = 0; i < 4; i++) bf[i] = *(const f16x8*)(Bs + offB[i] + co);
#pragma unroll
      for (int mi = 0; mi < 4; mi++)
#pragma unroll
        for (int ni = 0; ni < 4; ni++)
          acc[mi][ni] = __builtin_amdgcn_mfma_f32_16x16x32_f16(
              af[mi], bf[ni], acc[mi][ni], 0, 0, 0);
    }
  }

  if (n0 >= 2 * D_) {
    // V column-block: fused transpose. vt[(b*16+h)*64+hd][s] with pad mask.
#pragma unroll
    for (int mi = 0; mi < 4; mi++) {
      const int mgb = m0 + wave_m * 64 + mi * 16 + quad * 4;
      const int b = mgb >> 11, s = mgb & (S_ - 1);
      const float mk0 = mask[mgb], mk1 = mask[mgb + 1];
      const float mk2 = mask[mgb + 2], mk3 = mask[mgb + 3];
#pragma unroll
      for (int ni = 0; ni < 4; ni++) {
        const int vcol = n0 - 2 * D_ + wave_n * 64 + ni * 16 + lcol;
        f16x4 v = { (f16)(acc[mi][ni][0] * mk0), (f16)(acc[mi][ni][1] * mk1),
                    (f16)(acc[mi][ni][2] * mk2), (f16)(acc[mi][ni][3] * mk3) };
        *(f16x4*)(vtout +
                  ((size_t)(b * 16 + (vcol >> 6)) * 64 + (vcol & 63)) * S_ + s) = v;
      }
    }
  } else {
    const bool kmask = (n0 >= D_);
#pragma unroll
    for (int mi = 0; mi < 4; mi++) {
#pragma unroll
      for (int r = 0; r < 4; r++) {
        int mg = m0 + wave_m * 64 + mi * 16 + quad * 4 + r;
        float mk = kmask ? mask[mg] : 1.0f;
#pragma unroll
        for (int ni = 0; ni < 4; ni++) {
          int ng = n0 + wave_n * 64 + ni * 16 + lcol;
          Cq[(size_t)mg * N3_ + ng] = (f16)(acc[mi][ni][r] * mk);
        }
      }
    }
  }
}

// ---------------------------------------------------------------------------
// Output-projection GEMM, 64x128 tile (wave 32x64, acc 2x4), BK=64,
// SINGLE-buffer 2-barrier staging (measured-better structure). Grid 512 =
// 2 blocks/CU. f32 out + bias.
__global__ __launch_bounds__(256)
void gemm_proj(const f16* __restrict__ A, const f16* __restrict__ Bw,
               float* __restrict__ Cf, const float* __restrict__ bias) {
  __shared__ f16 As[64 * 64];
  __shared__ f16 Bs[128 * 64];

  const int tid  = threadIdx.x;
  const int lane = tid & 63;
  const int w    = tid >> 6;
  const int lcol = lane & 15;
  const int quad = lane >> 4;
  const int lx   = lcol & 7;
  const int wave_m = w >> 1, wave_n = w & 1;

  const int m0 = blockIdx.y * 64;
  const int n0 = blockIdx.x * 128;

  const int rr  = lane >> 3;
  const int gch = (lane & 7) ^ rr;

  const f16* gA[2];
  const f16* gB[4];
  f16* lA[2];
  f16* lB[4];
#pragma unroll
  for (int i = 0; i < 2; i++) {
    int seg = 2 * w + i;
    gA[i] = A + (size_t)(m0 + seg * 8 + rr) * D_ + gch * 8;
    lA[i] = As + seg * 512;
  }
#pragma unroll
  for (int i = 0; i < 4; i++) {
    int seg = i * 4 + w;
    gB[i] = Bw + (size_t)(n0 + seg * 8 + rr) * D_ + gch * 8;
    lB[i] = Bs + seg * 512;
  }

  int offA[2], offB[4];
#pragma unroll
  for (int i = 0; i < 2; i++) offA[i] = (wave_m * 32 + i * 16 + lcol) * 64;
#pragma unroll
  for (int i = 0; i < 4; i++) offB[i] = (wave_n * 64 + i * 16 + lcol) * 64;

  const f32x4 zero = {0.f, 0.f, 0.f, 0.f};
  f32x4 acc[2][4];
#pragma unroll
  for (int i = 0; i < 2; i++)
#pragma unroll
    for (int j = 0; j < 4; j++) acc[i][j] = zero;

  for (int k0 = 0; k0 < D_; k0 += 64) {
    __syncthreads();
#pragma unroll
    for (int i = 0; i < 2; i++) async16(gA[i] + k0, lA[i]);
#pragma unroll
    for (int i = 0; i < 4; i++) async16(gB[i] + k0, lB[i]);
    __syncthreads();

#pragma unroll
    for (int ks = 0; ks < 2; ks++) {
      const int co = ((quad + 4 * ks) ^ lx) * 8;
      f16x8 af[2], bf[4];
#pragma unroll
      for (int i = 0; i < 2; i++) af[i] = *(const f16x8*)(As + offA[i] + co);
#pragma unroll
      for (int i = 0; i < 4; i++) bf[i] = *(const f16x8*)(Bs + offB[i] + co);
#pragma unroll
      for (int mi = 0; mi < 2; mi++)
#pragma unroll
        for (int ni = 0; ni < 4; ni++)
          acc[mi][ni] = __builtin_amdgcn_mfma_f32_16x16x32_f16(
              af[mi], bf[ni], acc[mi][ni], 0, 0, 0);
    }
  }

#pragma unroll
  for (int mi = 0; mi < 2; mi++) {
#pragma unroll
    for (int r = 0; r < 4; r++) {
      int mg = m0 + wave_m * 32 + mi * 16 + quad * 4 + r;
#pragma unroll
      for (int ni = 0; ni < 4; ni++) {
        int ng = n0 + wave_n * 64 + ni * 16 + lcol;
        Cf[(size_t)mg * D_ + ng] = acc[mi][ni][r] + bias[ng];
      }
    }
  }
}

// ---------------------------------------------------------------------------
// Flash attention v7: 128-KEY TILES (17 barrier pairs/block instead of 34),
// dual-supertile, transposed-S, no-max softmax, ones-row MFMA row-sum.
// The no-max softmax has NO cross-tile coupling, so the inner loop fuses
// QK -> exp2 -> PV per 16-key column group (ct) — live registers stay flat.
// K tile: 128 rows x 128B [key][hd]; V^T tile: 64 rows x 256B [hd][key].
// XOR chunk swizzle on the global side (async16 dest is lane-linear).
__global__ __launch_bounds__(256)
void flash_attn7(const f16* __restrict__ qkv, const f16* __restrict__ vt,
                 f16* __restrict__ ctx) {
  __shared__ f16 Ks[128 * 64];   // 16 KB
  __shared__ f16 Vs[64 * 128];   // 16 KB

  const int tid  = threadIdx.x;
  const int lane = tid & 63;
  const int w    = tid >> 6;
  const int lcol = lane & 15;
  const int quad = lane >> 4;
  const int lx   = lcol & 7;

  const int id   = blockIdx.x;
  const int bh   = (id & 7) + 8 * ((id >> 3) & 3);
  const int pair = id >> 5;                  // 0..15
  const int b    = bh >> 4, h = bh & 15;
  const int qtA  = 31 - pair;                // big supertile (64 q-rows)
  const int qtB  = pair;                     // small supertile
  const int ktA  = qtA >> 1;                 // last 128-key tile for A
  const int ktB  = qtB >> 1;

  // K staging: 4 issues; issue i: row = 32i + 8w + (lane>>3), phys chunk lane&7
  const int rsub = lane >> 3;
  const int gchK = (lane & 7) ^ rsub;        // row&7 == rsub
  // V staging: 4 issues; issue i: row = 16i + 4w + (lane>>4), phys chunk lane&15
  const int vsub = lane >> 4;
  const int gchV = (lane & 15) ^ ((w * 4 + vsub) & 7);
  const f16* Kg = qkv + (size_t)b * S_ * N3_ + D_ + h * HD_;  // row stride N3
  const f16* Vg = vt + (size_t)bh * HD_ * S_;                 // row stride S

  const f32x4 zero = {0.f, 0.f, 0.f, 0.f};

  const int qrowA = qtA * 64 + w * 16 + lcol;
  const int qrowB = qtB * 64 + w * 16 + lcol;
  const f16* QpA = qkv + (size_t)(b * S_ + qrowA) * N3_ + h * HD_;
  const f16* QpB = qkv + (size_t)(b * S_ + qrowB) * N3_ + h * HD_;
  const f16x8 qbA0 = *(const f16x8*)(QpA + quad * 8);
  const f16x8 qbA1 = *(const f16x8*)(QpA + 32 + quad * 8);
  const f16x8 qbB0 = *(const f16x8*)(QpB + quad * 8);
  const f16x8 qbB1 = *(const f16x8*)(QpB + 32 + quad * 8);

  f32x4 oA[4], oB[4];
  f32x4 sumA = zero, sumB = zero;
#pragma unroll
  for (int i = 0; i < 4; i++) { oA[i] = zero; oB[i] = zero; }

  const f16 one_h = (f16)(lcol == 0 ? 1.0f : 0.0f);
  const f16x4 af_ones = { one_h, one_h, one_h, one_h };

  for (int kt = 0; kt <= ktA; kt++) {
    const int kbase = kt * 128;
    __syncthreads();                 // all waves done reading previous tile
#pragma unroll
    for (int i = 0; i < 4; i++) {
      async16(Kg + (size_t)(kbase + 32 * i + w * 8 + rsub) * N3_ + gchK * 8,
              Ks + (32 * i + w * 8) * 64);
      async16(Vg + (size_t)(16 * i + w * 4 + vsub) * S_ + kbase + gchV * 8,
              Vs + (16 * i + w * 4) * 128);
    }
    __syncthreads();                 // staging drained

    const bool doB = (kt <= ktB);
    const bool dgA = (kt == ktA);
    const bool dgB = (kt == ktB);

#pragma unroll
    for (int ct = 0; ct < 8; ct++) {
      const f16* kr = Ks + (ct * 16 + lcol) * 64;
      f16x8 k0 = *(const f16x8*)(kr + ((quad    ) ^ lx) * 8);
      f16x8 k1 = *(const f16x8*)(kr + ((quad + 4) ^ lx) * 8);

      f32x4 scA = zero;
      scA = __builtin_amdgcn_mfma_f32_16x16x32_f16(k0, qbA0, scA, 0, 0, 0);
      scA = __builtin_amdgcn_mfma_f32_16x16x32_f16(k1, qbA1, scA, 0, 0, 0);
      if (dgA) {
        const int kg = kbase + ct * 16 + quad * 4;
#pragma unroll
        for (int r = 0; r < 4; r++)
          if (kg + r > qrowA - qtA * 64 + qtA * 64) {}  // (folded below)
#pragma unroll
        for (int r = 0; r < 4; r++)
          if (kg + r > qrowA) scA[r] = -1e30f;
      }
      f16x2 la = pkrtz(exp2f(scA[0]), exp2f(scA[1]));
      f16x2 ha = pkrtz(exp2f(scA[2]), exp2f(scA[3]));
      f16x4 pA = { la[0], la[1], ha[0], ha[1] };
      sumA = __builtin_amdgcn_mfma_f32_16x16x16f16(af_ones, pA, sumA, 0, 0, 0);

      f16x4 pB;
      if (doB) {
        f32x4 scB = zero;
        scB = __builtin_amdgcn_mfma_f32_16x16x32_f16(k0, qbB0, scB, 0, 0, 0);
        scB = __builtin_amdgcn_mfma_f32_16x16x32_f16(k1, qbB1, scB, 0, 0, 0);
        if (dgB) {
          const int kg = kbase + ct * 16 + quad * 4;
#pragma unroll
          for (int r = 0; r < 4; r++)
            if (kg + r > qrowB) scB[r] = -1e30f;
        }
        f16x2 lb = pkrtz(exp2f(scB[0]), exp2f(scB[1]));
        f16x2 hb = pkrtz(exp2f(scB[2]), exp2f(scB[3]));
        f16x4 p = { lb[0], lb[1], hb[0], hb[1] };
        pB = p;
        sumB = __builtin_amdgcn_mfma_f32_16x16x16f16(af_ones, pB, sumB, 0, 0, 0);
      }

#pragma unroll
      for (int ht = 0; ht < 4; ht++) {
        const f16* vr = Vs + (ht * 16 + lcol) * 128;
        f16x4 vf = *(const f16x4*)(vr + (((2 * ct + (quad >> 1)) ^ lx) * 8) +
                                   (quad & 1) * 4);
        oA[ht] = __builtin_amdgcn_mfma_f32_16x16x16f16(vf, pA, oA[ht], 0, 0, 0);
        if (doB)
          oB[ht] = __builtin_amdgcn_mfma_f32_16x16x16f16(vf, pB, oB[ht], 0, 0, 0);
      }
    }
  }

  // lp lives in row 0 of sum tiles: lane (quad=0, col=lcol), element [0]
  const float lpA = __shfl(sumA[0], lcol);
  const float lpB = __shfl(sumB[0], lcol);
  const float invA = 1.f / lpA;
  const float invB = 1.f / lpB;
  f16* cpA = ctx + (size_t)(b * S_ + qrowA) * D_ + h * HD_ + quad * 4;
  f16* cpB = ctx + (size_t)(b * S_ + qrowB) * D_ + h * HD_ + quad * 4;
#pragma unroll
  for (int ht = 0; ht < 4; ht++) {
    f16x4 ovA = { (f16)(oA[ht][0] * invA), (f16)(oA[ht][1] * invA),
                  (f16)(oA[ht][2] * invA), (f16)(oA[ht][3] * invA) };
    *(f16x4*)(cpA + ht * 16) = ovA;
    f16x4 ovB = { (f16)(oB[ht][0] * invB), (f16)(oB[ht][1] * invB),
                  (f16)(oB[ht][2] * invB), (f16)(oB[ht][3] * invB) };
    *(f16x4*)(cpB + ht * 16) = ovB;
  }
}

// ---------------------------------------------------------------------------
extern "C" void kernel_launch(void* const* d_in, const int* in_sizes, int n_in,
                              void* d_out, int out_size, void* d_ws, size_t ws_size,
                              hipStream_t stream) {
  (void)in_sizes; (void)n_in; (void)out_size; (void)ws_size;
  const float* x  = (const float*)d_in[0];
  const float* am = (const float*)d_in[1];
  const float* Wq = (const float*)d_in[2];
  const float* Wk = (const float*)d_in[3];
  const float* Wv = (const float*)d_in[4];
  const float* Wo = (const float*)d_in[5];
  const float* bo = (const float*)d_in[6];
  float* out = (float*)d_out;

  f16* ws   = (f16*)d_ws;
  f16* wqkv = ws;                                   // 3*D*D   (Wq|Wk|Wv, NxK)
  f16* wo16 = wqkv + (size_t)3 * D_ * D_;           // D*D
  f16* xb   = wo16 + (size_t)D_ * D_;               // M*D
  f16* qkvb = xb + (size_t)M_ * D_;                 // M*3D  (Q|K cols used)
  f16* vtb  = qkvb + (size_t)M_ * N3_;              // B*H*HD*S
  f16* ctxb = vtb + (size_t)M_ * D_;                // M*D

  const float qscale = 0.125f * 1.4426950408889634f;  // 1/sqrt(hd) * log2(e)

  cvt_all<<<dim3((M_ * D_ + 4 * D_ * D_) / 1024), 256, 0, stream>>>(
      x, Wq, Wk, Wv, Wo, xb, wqkv, qscale);

  gemm_qkv<<<dim3(N3_ / 128, M_ / 128), 256, 0, stream>>>(
      xb, wqkv, qkvb, vtb, am);
  flash_attn7<<<dim3(512), 256, 0, stream>>>(qkvb, vtb, ctxb);
  gemm_proj<<<dim3(D_ / 128, M_ / 64), 256, 0, stream>>>(
      ctxb, wo16, out, bo);
}

// Round 11
// 187.267 us; speedup vs baseline: 1.0972x; 1.0972x over previous
//
#include <hip/hip_runtime.h>

// Problem constants
#define B_  2
#define S_  2048
#define D_  1024
#define H_  16
#define HD_ 64
#define N3_ 3072      // 3*D
#define M_  4096      // B*S

typedef _Float16 f16;
typedef _Float16 f16x2 __attribute__((ext_vector_type(2)));
typedef _Float16 f16x4 __attribute__((ext_vector_type(4)));
typedef _Float16 f16x8 __attribute__((ext_vector_type(8)));
typedef float    f32x4 __attribute__((ext_vector_type(4)));

// ---------------------------------------------------------------------------
// async global->LDS, 16B per lane. LDS dest must be wave-uniform base+lane*16.
__device__ __forceinline__ void async16(const f16* g, f16* l) {
  __builtin_amdgcn_global_load_lds(
      (const __attribute__((address_space(1))) unsigned int*)g,
      (__attribute__((address_space(3))) unsigned int*)l, 16, 0, 0);
}

__device__ __forceinline__ f16x2 pkrtz(float a, float b) {
  return __builtin_bit_cast(f16x2, __builtin_amdgcn_cvt_pkrtz(a, b));
}

// ---------------------------------------------------------------------------
// One launch converts x AND all 4 weight matrices to f16.
__global__ __launch_bounds__(256)
void cvt_all(const float* __restrict__ x,
             const float* __restrict__ Wq, const float* __restrict__ Wk,
             const float* __restrict__ Wv, const float* __restrict__ Wo,
             f16* __restrict__ xb, f16* __restrict__ wdst, float qscale) {
  const int i = blockIdx.x * 256 + threadIdx.x;
  const int XN4 = M_ * D_ / 4;          // 1048576
  const int WN4 = D_ * D_ / 4;          // 262144 = 2^18
  const float* src;
  f16* dst;
  float scale = 1.0f;
  int j;
  if (i < XN4) {
    src = x; dst = xb; j = i;
  } else {
    int k = i - XN4;
    int m = k >> 18;                    // which weight matrix
    j = k & (WN4 - 1);
    src = (m == 0) ? Wq : (m == 1) ? Wk : (m == 2) ? Wv : Wo;
    if (m == 0) scale = qscale;
    dst = wdst + (size_t)m * D_ * D_;
  }
  float4 v = ((const float4*)src)[j];
  f16x4 o = { (f16)(v.x * scale), (f16)(v.y * scale),
              (f16)(v.z * scale), (f16)(v.w * scale) };
  ((f16x4*)dst)[j] = o;
}

// ---------------------------------------------------------------------------
// QKV GEMM — round-6 single-buffer structure (measured 49.8 µs). 128x128
// tile, BK=64, async16 staging between two barriers. Q/K col-blocks -> f16
// Cq (mask on K); V col-blocks (n0>=2048) -> V^T into vtout (fused transpose).
__global__ __launch_bounds__(256)
void gemm_qkv(const f16* __restrict__ A, const f16* __restrict__ Bw,
              f16* __restrict__ Cq, f16* __restrict__ vtout,
              const float* __restrict__ mask) {
  __shared__ f16 As[128 * 64];
  __shared__ f16 Bs[128 * 64];

  const int tid  = threadIdx.x;
  const int lane = tid & 63;
  const int w    = tid >> 6;
  const int lcol = lane & 15;
  const int quad = lane >> 4;
  const int lx   = lcol & 7;
  const int wave_m = w >> 1, wave_n = w & 1;

  const int m0 = blockIdx.y * 128;
  const int n0 = blockIdx.x * 128;

  const int rr  = lane >> 3;
  const int gch = (lane & 7) ^ rr;

  const f16* gA[4];
  const f16* gB[4];
  f16* lA[4];
  f16* lB[4];
#pragma unroll
  for (int i = 0; i < 4; i++) {
    int seg = i * 4 + w;
    int row = seg * 8 + rr;
    gA[i] = A  + (size_t)(m0 + row) * D_ + gch * 8;
    gB[i] = Bw + (size_t)(n0 + row) * D_ + gch * 8;
    lA[i] = As + seg * 512;
    lB[i] = Bs + seg * 512;
  }

  int offA[4], offB[4];
#pragma unroll
  for (int i = 0; i < 4; i++) {
    offA[i] = (wave_m * 64 + i * 16 + lcol) * 64;
    offB[i] = (wave_n * 64 + i * 16 + lcol) * 64;
  }

  const f32x4 zero = {0.f, 0.f, 0.f, 0.f};
  f32x4 acc[4][4];
#pragma unroll
  for (int i = 0; i < 4; i++)
#pragma unroll
    for (int j = 0; j < 4; j++) acc[i][j] = zero;

  for (int k0 = 0; k0 < D_; k0 += 64) {
    __syncthreads();
#pragma unroll
    for (int i = 0; i < 4; i++) async16(gA[i] + k0, lA[i]);
#pragma unroll
    for (int i = 0; i < 4; i++) async16(gB[i] + k0, lB[i]);
    __syncthreads();

#pragma unroll
    for (int ks = 0; ks < 2; ks++) {
      const int co = ((quad + 4 * ks) ^ lx) * 8;
      f16x8 af[4], bf[4];
#pragma unroll
      for (int i = 0; i < 4; i++) af[i] = *(const f16x8*)(As + offA[i] + co);
#pragma unroll
      for (int i = 0; i < 4; i++) bf[i] = *(const f16x8*)(Bs + offB[i] + co);
#pragma unroll
      for (int mi = 0; mi < 4; mi++)
#pragma unroll
        for (int ni = 0; ni < 4; ni++)
          acc[mi][ni] = __builtin_amdgcn_mfma_f32_16x16x32_f16(
              af[mi], bf[ni], acc[mi][ni], 0, 0, 0);
    }
  }

  if (n0 >= 2 * D_) {
    // V column-block: fused transpose. vt[(b*16+h)*64+hd][s] with pad mask.
#pragma unroll
    for (int mi = 0; mi < 4; mi++) {
      const int mgb = m0 + wave_m * 64 + mi * 16 + quad * 4;
      const int b = mgb >> 11, s = mgb & (S_ - 1);
      const float mk0 = mask[mgb], mk1 = mask[mgb + 1];
      const float mk2 = mask[mgb + 2], mk3 = mask[mgb + 3];
#pragma unroll
      for (int ni = 0; ni < 4; ni++) {
        const int vcol = n0 - 2 * D_ + wave_n * 64 + ni * 16 + lcol;
        f16x4 v = { (f16)(acc[mi][ni][0] * mk0), (f16)(acc[mi][ni][1] * mk1),
                    (f16)(acc[mi][ni][2] * mk2), (f16)(acc[mi][ni][3] * mk3) };
        *(f16x4*)(vtout +
                  ((size_t)(b * 16 + (vcol >> 6)) * 64 + (vcol & 63)) * S_ + s) = v;
      }
    }
  } else {
    const bool kmask = (n0 >= D_);
#pragma unroll
    for (int mi = 0; mi < 4; mi++) {
#pragma unroll
      for (int r = 0; r < 4; r++) {
        int mg = m0 + wave_m * 64 + mi * 16 + quad * 4 + r;
        float mk = kmask ? mask[mg] : 1.0f;
#pragma unroll
        for (int ni = 0; ni < 4; ni++) {
          int ng = n0 + wave_n * 64 + ni * 16 + lcol;
          Cq[(size_t)mg * N3_ + ng] = (f16)(acc[mi][ni][r] * mk);
        }
      }
    }
  }
}

// ---------------------------------------------------------------------------
// Output-projection GEMM, 64x128 tile (wave 32x64, acc 2x4), BK=64,
// single-buffer 2-barrier staging. Grid 512 = 2 blocks/CU. f32 out + bias.
__global__ __launch_bounds__(256)
void gemm_proj(const f16* __restrict__ A, const f16* __restrict__ Bw,
               float* __restrict__ Cf, const float* __restrict__ bias) {
  __shared__ f16 As[64 * 64];
  __shared__ f16 Bs[128 * 64];

  const int tid  = threadIdx.x;
  const int lane = tid & 63;
  const int w    = tid >> 6;
  const int lcol = lane & 15;
  const int quad = lane >> 4;
  const int lx   = lcol & 7;
  const int wave_m = w >> 1, wave_n = w & 1;

  const int m0 = blockIdx.y * 64;
  const int n0 = blockIdx.x * 128;

  const int rr  = lane >> 3;
  const int gch = (lane & 7) ^ rr;

  const f16* gA[2];
  const f16* gB[4];
  f16* lA[2];
  f16* lB[4];
#pragma unroll
  for (int i = 0; i < 2; i++) {
    int seg = 2 * w + i;
    gA[i] = A + (size_t)(m0 + seg * 8 + rr) * D_ + gch * 8;
    lA[i] = As + seg * 512;
  }
#pragma unroll
  for (int i = 0; i < 4; i++) {
    int seg = i * 4 + w;
    gB[i] = Bw + (size_t)(n0 + seg * 8 + rr) * D_ + gch * 8;
    lB[i] = Bs + seg * 512;
  }

  int offA[2], offB[4];
#pragma unroll
  for (int i = 0; i < 2; i++) offA[i] = (wave_m * 32 + i * 16 + lcol) * 64;
#pragma unroll
  for (int i = 0; i < 4; i++) offB[i] = (wave_n * 64 + i * 16 + lcol) * 64;

  const f32x4 zero = {0.f, 0.f, 0.f, 0.f};
  f32x4 acc[2][4];
#pragma unroll
  for (int i = 0; i < 2; i++)
#pragma unroll
    for (int j = 0; j < 4; j++) acc[i][j] = zero;

  for (int k0 = 0; k0 < D_; k0 += 64) {
    __syncthreads();
#pragma unroll
    for (int i = 0; i < 2; i++) async16(gA[i] + k0, lA[i]);
#pragma unroll
    for (int i = 0; i < 4; i++) async16(gB[i] + k0, lB[i]);
    __syncthreads();

#pragma unroll
    for (int ks = 0; ks < 2; ks++) {
      const int co = ((quad + 4 * ks) ^ lx) * 8;
      f16x8 af[2], bf[4];
#pragma unroll
      for (int i = 0; i < 2; i++) af[i] = *(const f16x8*)(As + offA[i] + co);
#pragma unroll
      for (int i = 0; i < 4; i++) bf[i] = *(const f16x8*)(Bs + offB[i] + co);
#pragma unroll
      for (int mi = 0; mi < 2; mi++)
#pragma unroll
        for (int ni = 0; ni < 4; ni++)
          acc[mi][ni] = __builtin_amdgcn_mfma_f32_16x16x32_f16(
              af[mi], bf[ni], acc[mi][ni], 0, 0, 0);
    }
  }

#pragma unroll
  for (int mi = 0; mi < 2; mi++) {
#pragma unroll
    for (int r = 0; r < 4; r++) {
      int mg = m0 + wave_m * 32 + mi * 16 + quad * 4 + r;
#pragma unroll
      for (int ni = 0; ni < 4; ni++) {
        int ng = n0 + wave_n * 64 + ni * 16 + lcol;
        Cf[(size_t)mg * D_ + ng] = acc[mi][ni][r] + bias[ng];
      }
    }
  }
}

// ---------------------------------------------------------------------------
// Flash attention v4 (round-6 measured-best structure): 64-key tiles,
// phase-separated QK / softmax / PV (max ILP), merged dual-supertile,
// transposed-S, no-max softmax (p = exp2(s) directly), scalar lp adds,
// K/V frags loaded once and shared between A and B streams. XCD-swizzled
// 1-D grid (all 16 blocks of a (b,h) on one XCD -> L2-resident K/V).
__global__ __launch_bounds__(256)
void flash_attn4(const f16* __restrict__ qkv, const f16* __restrict__ vt,
                 f16* __restrict__ ctx) {
  __shared__ f16 Ks[64 * 64];   // [key][hd], 128B rows, chunk-swizzled
  __shared__ f16 Vs[64 * 64];   // [hd][key]

  const int tid  = threadIdx.x;
  const int lane = tid & 63;
  const int w    = tid >> 6;
  const int lcol = lane & 15;
  const int quad = lane >> 4;
  const int lx   = lcol & 7;

  const int id   = blockIdx.x;
  const int bh   = (id & 7) + 8 * ((id >> 3) & 3);
  const int pair = id >> 5;                  // 0..15
  const int b    = bh >> 4, h = bh & 15;
  const int qtA  = 31 - pair;                // big supertile
  const int qtB  = pair;                     // small supertile

  const int rsub = lane >> 3;
  const int gch  = (lane & 7) ^ rsub;
  const int krow0 = w * 8 + rsub;
  const int krow1 = 32 + w * 8 + rsub;
  const f16* Kg = qkv + (size_t)b * S_ * N3_ + D_ + h * HD_;  // row stride N3
  const f16* Vg = vt + (size_t)bh * HD_ * S_;                 // row stride S
  f16* ldsK0 = Ks + (w * 8) * 64;
  f16* ldsK1 = Ks + (32 + w * 8) * 64;
  f16* ldsV0 = Vs + (w * 8) * 64;
  f16* ldsV1 = Vs + (32 + w * 8) * 64;

  const f32x4 zero = {0.f, 0.f, 0.f, 0.f};

  const int qrowA = qtA * 64 + w * 16 + lcol;
  const int qrowB = qtB * 64 + w * 16 + lcol;
  const f16* QpA = qkv + (size_t)(b * S_ + qrowA) * N3_ + h * HD_;
  const f16* QpB = qkv + (size_t)(b * S_ + qrowB) * N3_ + h * HD_;
  const f16x8 qbA0 = *(const f16x8*)(QpA + quad * 8);
  const f16x8 qbA1 = *(const f16x8*)(QpA + 32 + quad * 8);
  const f16x8 qbB0 = *(const f16x8*)(QpB + quad * 8);
  const f16x8 qbB1 = *(const f16x8*)(QpB + 32 + quad * 8);

  f32x4 oA[4], oB[4];
  float lpA = 0.f, lpB = 0.f;
#pragma unroll
  for (int i = 0; i < 4; i++) { oA[i] = zero; oB[i] = zero; }

  auto mask_diag = [&](f32x4* sc) {
#pragma unroll
    for (int ct = 0; ct < 4; ct++) {
      int koff = ct * 16 + quad * 4;
      int qoff = w * 16 + lcol;
#pragma unroll
      for (int r = 0; r < 4; r++)
        if (koff + r > qoff) sc[ct][r] = -1e30f;
    }
  };
  auto softmax_tiles = [&](f32x4* sc, f16x4* pf, float& lp) {
#pragma unroll
    for (int ct = 0; ct < 4; ct++) {
      float e0 = exp2f(sc[ct][0]);
      float e1 = exp2f(sc[ct][1]);
      float e2 = exp2f(sc[ct][2]);
      float e3 = exp2f(sc[ct][3]);
      lp += (e0 + e1) + (e2 + e3);
      f16x2 lo = pkrtz(e0, e1);
      f16x2 hi = pkrtz(e2, e3);
      f16x4 p = { lo[0], lo[1], hi[0], hi[1] };
      pf[ct] = p;
    }
  };

  for (int kt = 0; kt <= qtA; kt++) {
    const int kbase = kt * 64;
    __syncthreads();
    async16(Kg + (size_t)(kbase + krow0) * N3_ + gch * 8, ldsK0);
    async16(Kg + (size_t)(kbase + krow1) * N3_ + gch * 8, ldsK1);
    async16(Vg + (size_t)krow0 * S_ + kbase + gch * 8, ldsV0);
    async16(Vg + (size_t)krow1 * S_ + kbase + gch * 8, ldsV1);
    __syncthreads();

    const bool doB = (kt <= qtB);

    f16x8 kf0[4], kf1[4];
    f32x4 scA[4], scB[4];
#pragma unroll
    for (int ct = 0; ct < 4; ct++) {
      const f16* kr = Ks + (ct * 16 + lcol) * 64;
      kf0[ct] = *(const f16x8*)(kr + ((quad    ) ^ lx) * 8);
      kf1[ct] = *(const f16x8*)(kr + ((quad + 4) ^ lx) * 8);
      f32x4 z = zero;
      z = __builtin_amdgcn_mfma_f32_16x16x32_f16(kf0[ct], qbA0, z, 0, 0, 0);
      z = __builtin_amdgcn_mfma_f32_16x16x32_f16(kf1[ct], qbA1, z, 0, 0, 0);
      scA[ct] = z;
    }
    if (doB) {
#pragma unroll
      for (int ct = 0; ct < 4; ct++) {
        f32x4 z = zero;
        z = __builtin_amdgcn_mfma_f32_16x16x32_f16(kf0[ct], qbB0, z, 0, 0, 0);
        z = __builtin_amdgcn_mfma_f32_16x16x32_f16(kf1[ct], qbB1, z, 0, 0, 0);
        scB[ct] = z;
      }
    }

    if (kt == qtA) mask_diag(scA);
    if (doB && kt == qtB) mask_diag(scB);

    f16x4 pfA[4], pfB[4];
    softmax_tiles(scA, pfA, lpA);
    if (doB) softmax_tiles(scB, pfB, lpB);

#pragma unroll
    for (int ht = 0; ht < 4; ht++) {
      const f16* vr = Vs + (ht * 16 + lcol) * 64 + (quad & 1) * 4;
      f16x4 vf[4];
#pragma unroll
      for (int ct = 0; ct < 4; ct++)
        vf[ct] = *(const f16x4*)(vr + (((2 * ct + (quad >> 1)) ^ lx) * 8));
#pragma unroll
      for (int ct = 0; ct < 4; ct++)
        oA[ht] = __builtin_amdgcn_mfma_f32_16x16x16f16(vf[ct], pfA[ct], oA[ht], 0, 0, 0);
      if (doB) {
#pragma unroll
        for (int ct = 0; ct < 4; ct++)
          oB[ht] = __builtin_amdgcn_mfma_f32_16x16x16f16(vf[ct], pfB[ct], oB[ht], 0, 0, 0);
      }
    }
  }

  lpA += __shfl_xor(lpA, 16);
  lpA += __shfl_xor(lpA, 32);
  lpB += __shfl_xor(lpB, 16);
  lpB += __shfl_xor(lpB, 32);
  const float invA = 1.f / lpA;
  const float invB = 1.f / lpB;
  f16* cpA = ctx + (size_t)(b * S_ + qrowA) * D_ + h * HD_ + quad * 4;
  f16* cpB = ctx + (size_t)(b * S_ + qrowB) * D_ + h * HD_ + quad * 4;
#pragma unroll
  for (int ht = 0; ht < 4; ht++) {
    f16x4 ovA = { (f16)(oA[ht][0] * invA), (f16)(oA[ht][1] * invA),
                  (f16)(oA[ht][2] * invA), (f16)(oA[ht][3] * invA) };
    *(f16x4*)(cpA + ht * 16) = ovA;
    f16x4 ovB = { (f16)(oB[ht][0] * invB), (f16)(oB[ht][1] * invB),
                  (f16)(oB[ht][2] * invB), (f16)(oB[ht][3] * invB) };
    *(f16x4*)(cpB + ht * 16) = ovB;
  }
}

// ---------------------------------------------------------------------------
extern "C" void kernel_launch(void* const* d_in, const int* in_sizes, int n_in,
                              void* d_out, int out_size, void* d_ws, size_t ws_size,
                              hipStream_t stream) {
  (void)in_sizes; (void)n_in; (void)out_size; (void)ws_size;
  const float* x  = (const float*)d_in[0];
  const float* am = (const float*)d_in[1];
  const float* Wq = (const float*)d_in[2];
  const float* Wk = (const float*)d_in[3];
  const float* Wv = (const float*)d_in[4];
  const float* Wo = (const float*)d_in[5];
  const float* bo = (const float*)d_in[6];
  float* out = (float*)d_out;

  f16* ws   = (f16*)d_ws;
  f16* wqkv = ws;                                   // 3*D*D   (Wq|Wk|Wv, NxK)
  f16* wo16 = wqkv + (size_t)3 * D_ * D_;           // D*D
  f16* xb   = wo16 + (size_t)D_ * D_;               // M*D
  f16* qkvb = xb + (size_t)M_ * D_;                 // M*3D  (Q|K cols used)
  f16* vtb  = qkvb + (size_t)M_ * N3_;              // B*H*HD*S
  f16* ctxb = vtb + (size_t)M_ * D_;                // M*D

  const float qscale = 0.125f * 1.4426950408889634f;  // 1/sqrt(hd) * log2(e)

  cvt_all<<<dim3((M_ * D_ + 4 * D_ * D_) / 1024), 256, 0, stream>>>(
      x, Wq, Wk, Wv, Wo, xb, wqkv, qscale);

  gemm_qkv<<<dim3(N3_ / 128, M_ / 128), 256, 0, stream>>>(
      xb, wqkv, qkvb, vtb, am);
  flash_attn4<<<dim3(512), 256, 0, stream>>>(qkvb, vtb, ctxb);
  gemm_proj<<<dim3(D_ / 128, M_ / 64), 256, 0, stream>>>(
      ctxb, wo16, out, bo);
}